// Round 1
// baseline (357.655 us; speedup 1.0000x reference)
//
#include <hip/hip_runtime.h>
#include <hip/hip_bf16.h>
#include <stdint.h>

// T=1 => softmax over size-1 axis == 1 => attention output == V; q/k/RoPE dead.
// Pipeline: zero(G,U) -> router -> top-128 -> rms1 (V=bv, X1=x, Hb) ->
// V += Hb@wv -> X1 += V@wo -> rms2 -> G,U += H2b@{Wg,Wu} (dual) ->
// Mb=silu(G)*U + out copy/scatter -> out[sel] += Mb@Wd.
//
// GEMM design (round-3): barrier-free, LDS-free streaming. A (<=1.4MB) is
// L2-resident and loaded straight into MFMA A-fragment layout (16B/lane,
// k-contiguous). B (the 169MB weight stream) is loaded straight into
// B-fragment layout (8 strided dwords/lane, 64B segments per 16 lanes) and
// cvt_pk'd to bf16. Register double-buffer prefetches the next K-step so the
// compiler emits counted vmcnt (no vmcnt(0) barrier drain -- the round-2
// bottleneck: 2-barrier LDS pipeline at 2 blocks/CU = 1.39 TB/s, 17% HBM).
// Wave = 32 rows x 16 cols (4-way M-split per block shares one B-frag via
// L1); grids 3-5.4 blocks/CU; XCD-chunked swizzle keeps column-neighbor
// blocks (sharing 128B B lines) on the same XCD L2.

#define D_ 2048
#define I_ 5504
#define NROWS 256
#define KSEL 128

typedef __attribute__((ext_vector_type(8))) short short8;   // 8 x bf16
typedef __attribute__((ext_vector_type(4))) float floatx4;  // MFMA acc

__device__ __forceinline__ unsigned int pk2(float lo, float hi) {
  __hip_bfloat162 h = __float22bfloat162_rn(float2{lo, hi});  // v_cvt_pk_bf16_f32
  unsigned int u; __builtin_memcpy(&u, &h, 4); return u;
}

// ---------------- K0: zero G,U (contiguous 5636096 B) ----------------
__global__ void k_zero(float4* __restrict__ p, int n4) {
  int i = blockIdx.x * 256 + threadIdx.x;
  int st = gridDim.x * 256;
  for (; i < n4; i += st) p[i] = float4{0.f, 0.f, 0.f, 0.f};
}

// ---------------- K1: router scores ----------------
__global__ void k_router(const float* __restrict__ hid, const float* __restrict__ rw,
                         const float* __restrict__ rb, float* __restrict__ scores) {
  int b = blockIdx.x, t = threadIdx.x;
  const float4* x4 = (const float4*)(hid + (size_t)b * D_);
  const float4* w4 = (const float4*)rw;
  float s = 0.f;
#pragma unroll
  for (int c = 0; c < 2; ++c) {
    float4 xv = x4[t + c * 256], wv = w4[t + c * 256];
    s += xv.x * wv.x + xv.y * wv.y + xv.z * wv.z + xv.w * wv.w;
  }
  for (int o = 32; o; o >>= 1) s += __shfl_down(s, o);
  __shared__ float red[4];
  if ((t & 63) == 0) red[t >> 6] = s;
  __syncthreads();
  if (t == 0) scores[b] = red[0] + red[1] + red[2] + red[3] + rb[0];
}

// ---------------- K2: exact top-k, deterministic (rank == slot) ----------------
__global__ void k_select(const float* __restrict__ scores, const int* __restrict__ kptr,
                         int* __restrict__ sel, int* __restrict__ pos) {
  __shared__ float sv[NROWS];
  int t = threadIdx.x;
  sv[t] = scores[t];
  __syncthreads();
  float s = sv[t];
  int c = 0;
  for (int j = 0; j < NROWS; ++j) {
    float o = sv[j];
    c += (o > s) || (o == s && j < t);
  }
  int k = *kptr;                 // k_sel == 128 (grids sized for it)
  if (c < k) sel[c] = t;
  pos[t] = (c < k) ? c : -1;
}

// ---------------- K3: rms1, init V=bv, X1=x, H bf16 ----------------
__global__ void k_rms1(const float* __restrict__ hid, const int* __restrict__ sel,
                       const float* __restrict__ ln1, const float* __restrict__ bv,
                       unsigned short* __restrict__ Hb, float* __restrict__ V,
                       float* __restrict__ X1) {
  int i = blockIdx.x, t = threadIdx.x;
  int r = sel[i];
  const float4* x4 = (const float4*)(hid + (size_t)r * D_);
  float4 xa = x4[2 * t], xb = x4[2 * t + 1];
  float ss = xa.x * xa.x + xa.y * xa.y + xa.z * xa.z + xa.w * xa.w
           + xb.x * xb.x + xb.y * xb.y + xb.z * xb.z + xb.w * xb.w;
  for (int o = 32; o; o >>= 1) ss += __shfl_down(ss, o);
  __shared__ float red[4];
  if ((t & 63) == 0) red[t >> 6] = ss;
  __syncthreads();
  float inv = rsqrtf((red[0] + red[1] + red[2] + red[3]) * (1.0f / D_) + 1e-6f);
  const float4* w4 = (const float4*)ln1;
  float4 wa = w4[2 * t], wb = w4[2 * t + 1];
  union { unsigned int u[4]; uint4 q; } pk;
  pk.u[0] = pk2(xa.x * inv * wa.x, xa.y * inv * wa.y);
  pk.u[1] = pk2(xa.z * inv * wa.z, xa.w * inv * wa.w);
  pk.u[2] = pk2(xb.x * inv * wb.x, xb.y * inv * wb.y);
  pk.u[3] = pk2(xb.z * inv * wb.z, xb.w * inv * wb.w);
  ((uint4*)(Hb + (size_t)i * D_))[t] = pk.q;
  const float4* b4 = (const float4*)bv;
  float4* V4 = (float4*)(V + (size_t)i * D_);
  V4[2 * t] = b4[2 * t]; V4[2 * t + 1] = b4[2 * t + 1];
  float4* X4 = (float4*)(X1 + (size_t)i * D_);
  X4[2 * t] = xa; X4[2 * t + 1] = xb;
}

// ---------------- K5: rms2 (G/U zeroing moved to k_zero) ----------------
__global__ void k_rms2(const float* __restrict__ X1, const float* __restrict__ ln2,
                       unsigned short* __restrict__ H2b) {
  int i = blockIdx.x, t = threadIdx.x;
  const float4* x4 = (const float4*)(X1 + (size_t)i * D_);
  float4 xa = x4[2 * t], xb = x4[2 * t + 1];
  float ss = xa.x * xa.x + xa.y * xa.y + xa.z * xa.z + xa.w * xa.w
           + xb.x * xb.x + xb.y * xb.y + xb.z * xb.z + xb.w * xb.w;
  for (int o = 32; o; o >>= 1) ss += __shfl_down(ss, o);
  __shared__ float red[4];
  if ((t & 63) == 0) red[t >> 6] = ss;
  __syncthreads();
  float inv = rsqrtf((red[0] + red[1] + red[2] + red[3]) * (1.0f / D_) + 1e-6f);
  const float4* w4 = (const float4*)ln2;
  float4 wa = w4[2 * t], wb = w4[2 * t + 1];
  union { unsigned int u[4]; uint4 q; } pk;
  pk.u[0] = pk2(xa.x * inv * wa.x, xa.y * inv * wa.y);
  pk.u[1] = pk2(xa.z * inv * wa.z, xa.w * inv * wa.w);
  pk.u[2] = pk2(xb.x * inv * wb.x, xb.y * inv * wb.y);
  pk.u[3] = pk2(xb.z * inv * wb.z, xb.w * inv * wb.w);
  ((uint4*)(H2b + (size_t)i * D_))[t] = pk.q;
}

// ---------------- K7: Mb = silu(G)*U ; out = copy/scatter ----------------
__global__ void k_silu_out(const float* __restrict__ G, const float* __restrict__ U,
                           unsigned short* __restrict__ Mb,
                           const float* __restrict__ X1, const int* __restrict__ pos,
                           const float* __restrict__ hid, float* __restrict__ out) {
  int tid = blockIdx.x * 256 + threadIdx.x;
  const int nM4 = KSEL * I_ / 4;    // 176128
  if (tid < nM4) {
    float4 g = ((const float4*)G)[tid], u = ((const float4*)U)[tid];
    float m0 = (g.x / (1.f + expf(-g.x))) * u.x;
    float m1 = (g.y / (1.f + expf(-g.y))) * u.y;
    float m2 = (g.z / (1.f + expf(-g.z))) * u.z;
    float m3 = (g.w / (1.f + expf(-g.w))) * u.w;
    uint2 o; o.x = pk2(m0, m1); o.y = pk2(m2, m3);
    ((uint2*)Mb)[tid] = o;
  }
  const int nO4 = NROWS * (D_ / 4);   // 131072 float4
  if (tid < nO4) {
    int row = tid >> 9;             // 512 float4 per row
    int c4 = tid & 511;
    int p = pos[row];
    ((float4*)out)[tid] = (p >= 0) ? ((const float4*)X1)[(size_t)p * 512 + c4]
                                   : ((const float4*)hid)[tid];
  }
}

// ---------------- GEMM: C[128xN] += A[128xK] @ B[KxN], streaming ----------------
// Block = 256 thr = 4 waves, each wave = (32 rows, 16 cols): wave wq rows
// [wq*32, wq*32+32), block cols [bn*16, bn*16+16). All 4 waves read the SAME
// B-fragment (L1-shared). Split-K over SPLITS chunks of KC, atomic fp32 adds.
// No LDS, no barriers: A-frag = 16B/lane direct global load (bf16) or 2x
// float4 + cvt (fp32); B-frag = 8 strided dwords/lane + 4 cvt_pk. Register
// double-buffer (ra/rb) prefetches K-step k+32 while MFMAing step k, so the
// compiler emits counted vmcnt and B loads stay in flight across steps.
template<bool AF32, bool DUAL, int SPLITS, int LDA, int NN, int LDC>
__global__ __launch_bounds__(256, 3)
void k_gemm(const void* __restrict__ Ap, const float* __restrict__ B0,
            const float* __restrict__ B1, float* __restrict__ C0,
            float* __restrict__ C1, const int* __restrict__ rowmap,
            int K, int KC) {
  // XCD-chunked swizzle: nwg%8==0 for all grids; consecutive nid (same bn
  // neighborhood, all k-splits) land on one XCD -> B-line + A L2 locality.
  int nwg = gridDim.x;
  int id = blockIdx.x;
  int nid = (id & 7) * (nwg >> 3) + (id >> 3);
  int bn = nid / SPLITS;
  int ks = nid % SPLITS;
  int k0 = ks * KC;
  int k1 = k0 + KC; if (k1 > K) k1 = K;

  int tid = threadIdx.x;
  int lane = tid & 63, wq = tid >> 6;
  int fm = lane & 15, kq = lane >> 4;
  int colbase = bn * 16;

  const unsigned short* Ab = nullptr;
  const float* Af = nullptr;
  if constexpr (AF32) Af = (const float*)Ap + (size_t)(wq * 32 + fm) * LDA + kq * 8;
  else                Ab = (const unsigned short*)Ap + (size_t)(wq * 32 + fm) * LDA + kq * 8;
  // B base already at this lane's k-phase (k0 + kq*8) and column.
  const float* B0k = B0 + (size_t)(k0 + kq * 8) * NN + colbase + fm;
  const float* B1k = DUAL ? B1 + (size_t)(k0 + kq * 8) * NN + colbase + fm : nullptr;

  floatx4 acc0[2] = {};
  floatx4 acc1[2] = {};

  struct Regs {
    uint4 a[2];          // bf16 A path: frag i = rows wq*32+i*16+fm, 8 k-elems
    float4 af[2][2];     // fp32 A path
    float b0[8], b1[8];  // B column dwords, k = kq*8 + j
  };

  auto load = [&](Regs& r, int kk) {
    int dk = kk - k0;                       // uniform, >= 0
    if constexpr (AF32) {
#pragma unroll
      for (int i = 0; i < 2; ++i) {
        r.af[i][0] = *(const float4*)(Af + (size_t)(i * 16) * LDA + kk);
        r.af[i][1] = *(const float4*)(Af + (size_t)(i * 16) * LDA + kk + 4);
      }
    } else {
#pragma unroll
      for (int i = 0; i < 2; ++i)
        r.a[i] = *(const uint4*)(Ab + (size_t)(i * 16) * LDA + kk);
    }
    const float* bp = B0k + (size_t)dk * NN;
#pragma unroll
    for (int j = 0; j < 8; ++j) r.b0[j] = bp[(size_t)j * NN];
    if constexpr (DUAL) {
      const float* cp = B1k + (size_t)dk * NN;
#pragma unroll
      for (int j = 0; j < 8; ++j) r.b1[j] = cp[(size_t)j * NN];
    }
  };

  auto step = [&](Regs& r) {
    short8 a0, a1, bf0;
    union { unsigned int u[4]; short8 s; } cv;
    if constexpr (AF32) {
      cv.u[0] = pk2(r.af[0][0].x, r.af[0][0].y);
      cv.u[1] = pk2(r.af[0][0].z, r.af[0][0].w);
      cv.u[2] = pk2(r.af[0][1].x, r.af[0][1].y);
      cv.u[3] = pk2(r.af[0][1].z, r.af[0][1].w);
      a0 = cv.s;
      cv.u[0] = pk2(r.af[1][0].x, r.af[1][0].y);
      cv.u[1] = pk2(r.af[1][0].z, r.af[1][0].w);
      cv.u[2] = pk2(r.af[1][1].x, r.af[1][1].y);
      cv.u[3] = pk2(r.af[1][1].z, r.af[1][1].w);
      a1 = cv.s;
    } else {
      union { uint4 q; short8 s; } ua;
      ua.q = r.a[0]; a0 = ua.s;
      ua.q = r.a[1]; a1 = ua.s;
    }
    cv.u[0] = pk2(r.b0[0], r.b0[1]); cv.u[1] = pk2(r.b0[2], r.b0[3]);
    cv.u[2] = pk2(r.b0[4], r.b0[5]); cv.u[3] = pk2(r.b0[6], r.b0[7]);
    bf0 = cv.s;
    acc0[0] = __builtin_amdgcn_mfma_f32_16x16x32_bf16(a0, bf0, acc0[0], 0, 0, 0);
    acc0[1] = __builtin_amdgcn_mfma_f32_16x16x32_bf16(a1, bf0, acc0[1], 0, 0, 0);
    if constexpr (DUAL) {
      short8 bf1;
      cv.u[0] = pk2(r.b1[0], r.b1[1]); cv.u[1] = pk2(r.b1[2], r.b1[3]);
      cv.u[2] = pk2(r.b1[4], r.b1[5]); cv.u[3] = pk2(r.b1[6], r.b1[7]);
      bf1 = cv.s;
      acc1[0] = __builtin_amdgcn_mfma_f32_16x16x32_bf16(a0, bf1, acc1[0], 0, 0, 0);
      acc1[1] = __builtin_amdgcn_mfma_f32_16x16x32_bf16(a1, bf1, acc1[1], 0, 0, 0);
    }
  };

  Regs ra, rb;
  load(ra, k0);
  int kk = k0;
  while (true) {
    int nk = kk + 32;
    if (nk < k1) load(rb, nk);   // in flight while step(ra) runs
    step(ra);
    if (nk >= k1) break;
    kk = nk; nk += 32;
    if (nk < k1) load(ra, nk);
    step(rb);
    if (nk >= k1) break;
    kk = nk;
  }

  // epilogue (C/D layout: col=lane&15, row=(lane>>4)*4+reg)
#pragma unroll
  for (int i = 0; i < 2; ++i) {
#pragma unroll
    for (int r = 0; r < 4; ++r) {
      int row = wq * 32 + i * 16 + kq * 4 + r;
      size_t rbase = rowmap ? (size_t)rowmap[row] * LDC : (size_t)row * LDC;
      int col = colbase + fm;
      atomicAdd(&C0[rbase + col], acc0[i][r]);
      if constexpr (DUAL) atomicAdd(&C1[rbase + col], acc1[i][r]);
    }
  }
}

extern "C" void kernel_launch(void* const* d_in, const int* in_sizes, int n_in,
                              void* d_out, int out_size, void* d_ws, size_t ws_size,
                              hipStream_t stream) {
  const float* hid = (const float*)d_in[0];
  const float* rw  = (const float*)d_in[3];
  const float* rb  = (const float*)d_in[4];
  const float* ln1 = (const float*)d_in[5];
  const float* ln2 = (const float*)d_in[6];
  const float* wv  = (const float*)d_in[11];
  const float* bv  = (const float*)d_in[12];
  const float* wo  = (const float*)d_in[13];
  const float* wg  = (const float*)d_in[14];
  const float* wu  = (const float*)d_in[15];
  const float* wd  = (const float*)d_in[16];
  const int*   kp  = (const int*)d_in[17];
  float* out = (float*)d_out;

  char* ws = (char*)d_ws;
  float*          scores = (float*)(ws + 0);                // 1 KB
  int*            sel    = (int*)(ws + 1024);               // 512 B
  int*            pos    = (int*)(ws + 1536);               // 1 KB
  unsigned short* Hb     = (unsigned short*)(ws + 4096);    // 512 KB
  float*          V      = (float*)(ws + 528384);           // 1 MB
  float*          X1     = (float*)(ws + 1576960);          // 1 MB
  unsigned short* H2b    = (unsigned short*)(ws + 2625536); // 512 KB
  float*          G      = (float*)(ws + 3149824);          // 2.69 MB
  float*          U      = (float*)(ws + 5967872);          // 2.69 MB (contiguous with G)
  unsigned short* Mb     = (unsigned short*)(ws + 8785920); // 1.34 MB

  // zero G,U first (no deps; G..U contiguous 5636096 B = 352256 float4)
  k_zero<<<1024, 256, 0, stream>>>((float4*)G, 352256);
  k_router<<<256, 256, 0, stream>>>(hid, rw, rb, scores);
  k_select<<<1, 256, 0, stream>>>(scores, kp, sel, pos);
  k_rms1<<<128, 256, 0, stream>>>(hid, sel, ln1, bv, Hb, V, X1);
  // V += Hb @ wv   (128 n-tiles x 8 splits = 1024 blocks = 4/CU, KC=256)
  k_gemm<false, false, 8, 2048, 2048, 2048><<<1024, 256, 0, stream>>>(
      Hb, wv, nullptr, V, nullptr, nullptr, 2048, 256);
  // X1 += V @ wo  (A fp32)
  k_gemm<true, false, 8, 2048, 2048, 2048><<<1024, 256, 0, stream>>>(
      V, wo, nullptr, X1, nullptr, nullptr, 2048, 256);
  k_rms2<<<128, 256, 0, stream>>>(X1, ln2, H2b);
  // G,U += H2b @ {wg,wu}  (344 n-tiles x 4 splits = 1376 blocks = 5.4/CU, KC=512)
  k_gemm<false, true, 4, 2048, 5504, 5504><<<1376, 256, 0, stream>>>(
      H2b, wg, wu, G, U, nullptr, 2048, 512);
  k_silu_out<<<1024, 256, 0, stream>>>(G, U, Mb, X1, pos, hid, out);
  // out[sel] += Mb @ wd  (128 x 8 = 1024 blocks, KC=704, last chunk 576)
  k_gemm<false, false, 8, 5504, 2048, 2048><<<1024, 256, 0, stream>>>(
      Mb, wd, nullptr, out, nullptr, sel, 5504, 704);
}

// Round 2
// 309.129 us; speedup vs baseline: 1.1570x; 1.1570x over previous
//
#include <hip/hip_runtime.h>
#include <hip/hip_bf16.h>
#include <stdint.h>

// T=1 => softmax over size-1 axis == 1 => attention output == V; q/k/RoPE dead.
// Pipeline: zero(G,U) -> router -> top-128 -> rms1 (V=bv, X1=x, Hb) ->
// V += Hb@wv -> X1 += V@wo -> rms2 -> G,U += H2b@{Wg,Wu} (dual) ->
// Mb=silu(G)*U + out copy/scatter -> out[sel] += Mb@Wd.
//
// GEMM (round-4): round-0's proven LDS pipeline (128x32 tile, BK=64, 4 waves,
// register prefetch, split-K atomics) with two fixes:
//  (a) A-staging remapped so consecutive lanes load consecutive 16B
//      (8 rows x 128B coalesced lines per instruction) instead of the old
//      32-rows x 16B scatter (64 requests/instr) that serialized the TA.
//  (b) 4-5 blocks/CU instead of 2 (prior session: 1->2 blocks/CU was
//      1.16->1.39 TB/s; latency-bound, occupancy-scaled). launch_bounds(256,4).
// Round-1's LDS-free streaming GEMM regressed (840 GB/s): strided 4B B-frag
// loads + 1-step prefetch depth; reverted.

#define D_ 2048
#define I_ 5504
#define NROWS 256
#define KSEL 128

typedef __attribute__((ext_vector_type(8))) short short8;   // 8 x bf16
typedef __attribute__((ext_vector_type(4))) float floatx4;  // MFMA acc

__device__ __forceinline__ unsigned int pk2(float lo, float hi) {
  __hip_bfloat162 h = __float22bfloat162_rn(float2{lo, hi});  // v_cvt_pk_bf16_f32
  unsigned int u; __builtin_memcpy(&u, &h, 4); return u;
}

// ---------------- K0: zero G,U (contiguous 5636096 B) ----------------
__global__ void k_zero(float4* __restrict__ p, int n4) {
  int i = blockIdx.x * 256 + threadIdx.x;
  int st = gridDim.x * 256;
  for (; i < n4; i += st) p[i] = float4{0.f, 0.f, 0.f, 0.f};
}

// ---------------- K1: router scores ----------------
__global__ void k_router(const float* __restrict__ hid, const float* __restrict__ rw,
                         const float* __restrict__ rb, float* __restrict__ scores) {
  int b = blockIdx.x, t = threadIdx.x;
  const float4* x4 = (const float4*)(hid + (size_t)b * D_);
  const float4* w4 = (const float4*)rw;
  float s = 0.f;
#pragma unroll
  for (int c = 0; c < 2; ++c) {
    float4 xv = x4[t + c * 256], wv = w4[t + c * 256];
    s += xv.x * wv.x + xv.y * wv.y + xv.z * wv.z + xv.w * wv.w;
  }
  for (int o = 32; o; o >>= 1) s += __shfl_down(s, o);
  __shared__ float red[4];
  if ((t & 63) == 0) red[t >> 6] = s;
  __syncthreads();
  if (t == 0) scores[b] = red[0] + red[1] + red[2] + red[3] + rb[0];
}

// ---------------- K2: exact top-k, deterministic (rank == slot) ----------------
__global__ void k_select(const float* __restrict__ scores, const int* __restrict__ kptr,
                         int* __restrict__ sel, int* __restrict__ pos) {
  __shared__ float sv[NROWS];
  int t = threadIdx.x;
  sv[t] = scores[t];
  __syncthreads();
  float s = sv[t];
  int c = 0;
  for (int j = 0; j < NROWS; ++j) {
    float o = sv[j];
    c += (o > s) || (o == s && j < t);
  }
  int k = *kptr;                 // k_sel == 128 (grids sized for it)
  if (c < k) sel[c] = t;
  pos[t] = (c < k) ? c : -1;
}

// ---------------- K3: rms1, init V=bv, X1=x, H bf16 ----------------
__global__ void k_rms1(const float* __restrict__ hid, const int* __restrict__ sel,
                       const float* __restrict__ ln1, const float* __restrict__ bv,
                       unsigned short* __restrict__ Hb, float* __restrict__ V,
                       float* __restrict__ X1) {
  int i = blockIdx.x, t = threadIdx.x;
  int r = sel[i];
  const float4* x4 = (const float4*)(hid + (size_t)r * D_);
  float4 xa = x4[2 * t], xb = x4[2 * t + 1];
  float ss = xa.x * xa.x + xa.y * xa.y + xa.z * xa.z + xa.w * xa.w
           + xb.x * xb.x + xb.y * xb.y + xb.z * xb.z + xb.w * xb.w;
  for (int o = 32; o; o >>= 1) ss += __shfl_down(ss, o);
  __shared__ float red[4];
  if ((t & 63) == 0) red[t >> 6] = ss;
  __syncthreads();
  float inv = rsqrtf((red[0] + red[1] + red[2] + red[3]) * (1.0f / D_) + 1e-6f);
  const float4* w4 = (const float4*)ln1;
  float4 wa = w4[2 * t], wb = w4[2 * t + 1];
  union { unsigned int u[4]; uint4 q; } pk;
  pk.u[0] = pk2(xa.x * inv * wa.x, xa.y * inv * wa.y);
  pk.u[1] = pk2(xa.z * inv * wa.z, xa.w * inv * wa.w);
  pk.u[2] = pk2(xb.x * inv * wb.x, xb.y * inv * wb.y);
  pk.u[3] = pk2(xb.z * inv * wb.z, xb.w * inv * wb.w);
  ((uint4*)(Hb + (size_t)i * D_))[t] = pk.q;
  const float4* b4 = (const float4*)bv;
  float4* V4 = (float4*)(V + (size_t)i * D_);
  V4[2 * t] = b4[2 * t]; V4[2 * t + 1] = b4[2 * t + 1];
  float4* X4 = (float4*)(X1 + (size_t)i * D_);
  X4[2 * t] = xa; X4[2 * t + 1] = xb;
}

// ---------------- K5: rms2 (G/U zeroing in k_zero) ----------------
__global__ void k_rms2(const float* __restrict__ X1, const float* __restrict__ ln2,
                       unsigned short* __restrict__ H2b) {
  int i = blockIdx.x, t = threadIdx.x;
  const float4* x4 = (const float4*)(X1 + (size_t)i * D_);
  float4 xa = x4[2 * t], xb = x4[2 * t + 1];
  float ss = xa.x * xa.x + xa.y * xa.y + xa.z * xa.z + xa.w * xa.w
           + xb.x * xb.x + xb.y * xb.y + xb.z * xb.z + xb.w * xb.w;
  for (int o = 32; o; o >>= 1) ss += __shfl_down(ss, o);
  __shared__ float red[4];
  if ((t & 63) == 0) red[t >> 6] = ss;
  __syncthreads();
  float inv = rsqrtf((red[0] + red[1] + red[2] + red[3]) * (1.0f / D_) + 1e-6f);
  const float4* w4 = (const float4*)ln2;
  float4 wa = w4[2 * t], wb = w4[2 * t + 1];
  union { unsigned int u[4]; uint4 q; } pk;
  pk.u[0] = pk2(xa.x * inv * wa.x, xa.y * inv * wa.y);
  pk.u[1] = pk2(xa.z * inv * wa.z, xa.w * inv * wa.w);
  pk.u[2] = pk2(xb.x * inv * wb.x, xb.y * inv * wb.y);
  pk.u[3] = pk2(xb.z * inv * wb.z, xb.w * inv * wb.w);
  ((uint4*)(H2b + (size_t)i * D_))[t] = pk.q;
}

// ---------------- K7: Mb = silu(G)*U ; out = copy/scatter ----------------
__global__ void k_silu_out(const float* __restrict__ G, const float* __restrict__ U,
                           unsigned short* __restrict__ Mb,
                           const float* __restrict__ X1, const int* __restrict__ pos,
                           const float* __restrict__ hid, float* __restrict__ out) {
  int tid = blockIdx.x * 256 + threadIdx.x;
  const int nM4 = KSEL * I_ / 4;    // 176128
  if (tid < nM4) {
    float4 g = ((const float4*)G)[tid], u = ((const float4*)U)[tid];
    float m0 = (g.x / (1.f + expf(-g.x))) * u.x;
    float m1 = (g.y / (1.f + expf(-g.y))) * u.y;
    float m2 = (g.z / (1.f + expf(-g.z))) * u.z;
    float m3 = (g.w / (1.f + expf(-g.w))) * u.w;
    uint2 o; o.x = pk2(m0, m1); o.y = pk2(m2, m3);
    ((uint2*)Mb)[tid] = o;
  }
  const int nO4 = NROWS * (D_ / 4);   // 131072 float4
  if (tid < nO4) {
    int row = tid >> 9;             // 512 float4 per row
    int c4 = tid & 511;
    int p = pos[row];
    ((float4*)out)[tid] = (p >= 0) ? ((const float4*)X1)[(size_t)p * 512 + c4]
                                   : ((const float4*)hid)[tid];
  }
}

// ---------------- GEMM: C[128xN] += A[128xKA] @ B[KbxN] ----------------
// 128x32 tile, BK=64, 4 waves (2 wm x 2 wn), 16x16x32 bf16 MFMA.
// K = iteration space (KT*gridDim.y, may exceed KA for tail padding);
// A granules with col>=KA are zero-filled, B rows clamped to Kb-1 (harmless:
// multiplied by zero A). Register prefetch of next tile during MFMA phase.
// A staging: lane groups of 8 (bf16) / 16 (fp32) cover one contiguous row
// segment -> fully coalesced 128B lines per instruction.
template<bool AF32, bool DUAL>
__global__ __launch_bounds__(256, 4)
void k_gemm(const void* __restrict__ Ap, const float* __restrict__ B0,
            const float* __restrict__ B1, float* __restrict__ C0,
            float* __restrict__ C1, const int* __restrict__ rowmap,
            int K, int KA, int Kb, int lda, int N, int KT, int ldc) {
  constexpr int ST = 72;   // LDS stride (elems): 144 B rows, b128-aligned
  const int bn = blockIdx.x;
  const int kt0 = blockIdx.y * KT;
  const int kt1 = kt0 + KT;
  const int tid = threadIdx.x;
  const int lane = tid & 63;
  const int wave = tid >> 6;
  const int wm = wave >> 1, wn = wave & 1;
  const int fm = lane & 15, kq = lane >> 4;

  __shared__ alignas(16) unsigned short Asm[128 * ST];            // 18 KB
  __shared__ alignas(16) unsigned short Bsm0[32 * ST];            // 4.5 KB
  __shared__ alignas(16) unsigned short Bsm1[DUAL ? 32 * ST : 8];

  floatx4 acc0[4] = {};
  floatx4 acc1[4] = {};

  // A staging: bf16 path: pass r covers rows r*32+(t>>3), k-granule (t&7)*8
  //            fp32 path: pass r covers rows r*16+(t>>4), k-granule (t&15)*4
  const int arow = tid >> 3;
  const int akg  = (tid & 7) * 8;
  const int frow = tid >> 4;
  const int fkg  = (tid & 15) * 4;
  // B staging: thread -> (col bnn, 8-row group bk8); one ds_write_b128 per B
  const int bnn = tid & 31;
  const int bk8 = (tid >> 5) * 8;

  const unsigned short* Ab = AF32 ? nullptr : (const unsigned short*)Ap;
  const float*          Af = AF32 ? (const float*)Ap : nullptr;
  const float* B0c = B0 + (size_t)(bn * 32 + bnn);
  const float* B1c = DUAL ? B1 + (size_t)(bn * 32 + bnn) : nullptr;

  // prefetch registers
  uint4 a4[4];        // bf16 A: 4 x (row, 16B granule)
  float4 af8[8];      // fp32 A: 8 x (row, 16B granule)
  float b0v[8], b1v[8];

  auto load_tile = [&](int kt) {
    if (AF32) {
      const int c0 = kt + fkg;
      const bool ok = c0 < KA;
#pragma unroll
      for (int r = 0; r < 8; ++r) {
        const float* p = Af + (size_t)(r * 16 + frow) * lda + c0;
        af8[r] = ok ? *(const float4*)p : make_float4(0.f, 0.f, 0.f, 0.f);
      }
    } else {
      const int c0 = kt + akg;
      const bool ok = c0 < KA;
#pragma unroll
      for (int r = 0; r < 4; ++r) {
        const unsigned short* p = Ab + (size_t)(r * 32 + arow) * lda + c0;
        a4[r] = ok ? *(const uint4*)p : make_uint4(0u, 0u, 0u, 0u);
      }
    }
#pragma unroll
    for (int j = 0; j < 8; ++j) {
      int kr = kt + bk8 + j; kr = kr < Kb ? kr : Kb - 1;
      b0v[j] = B0c[(size_t)kr * N];
      if (DUAL) b1v[j] = B1c[(size_t)kr * N];
    }
  };

  load_tile(kt0);

  for (int kt = kt0; kt < kt1; kt += 64) {
    __syncthreads();   // previous iteration's LDS readers done
    // ---- store staged tile to LDS ----
    {
      if (AF32) {
#pragma unroll
        for (int r = 0; r < 8; ++r) {
          uint2 w;
          w.x = pk2(af8[r].x, af8[r].y);
          w.y = pk2(af8[r].z, af8[r].w);
          *(uint2*)&Asm[(r * 16 + frow) * ST + fkg] = w;
        }
      } else {
#pragma unroll
        for (int r = 0; r < 4; ++r)
          *(uint4*)&Asm[(r * 32 + arow) * ST + akg] = a4[r];
      }
      uint4 bq;
      bq.x = pk2(b0v[0], b0v[1]); bq.y = pk2(b0v[2], b0v[3]);
      bq.z = pk2(b0v[4], b0v[5]); bq.w = pk2(b0v[6], b0v[7]);
      *(uint4*)&Bsm0[bnn * ST + bk8] = bq;
      if (DUAL) {
        uint4 cq;
        cq.x = pk2(b1v[0], b1v[1]); cq.y = pk2(b1v[2], b1v[3]);
        cq.z = pk2(b1v[4], b1v[5]); cq.w = pk2(b1v[6], b1v[7]);
        *(uint4*)&Bsm1[bnn * ST + bk8] = cq;
      }
    }
    __syncthreads();   // tile visible
    // ---- prefetch next tile (hides behind MFMA below) ----
    if (kt + 64 < kt1) load_tile(kt + 64);
    // ---- fragments + MFMA (2 K-steps of 32) ----
    short8 afr[2][4], bf0[2], bf1[2];
#pragma unroll
    for (int s = 0; s < 2; ++s) {
#pragma unroll
      for (int i = 0; i < 4; ++i)
        afr[s][i] = *(const short8*)&Asm[(wm * 64 + i * 16 + fm) * ST + s * 32 + kq * 8];
      bf0[s] = *(const short8*)&Bsm0[(wn * 16 + fm) * ST + s * 32 + kq * 8];
      if (DUAL)
        bf1[s] = *(const short8*)&Bsm1[(wn * 16 + fm) * ST + s * 32 + kq * 8];
    }
#pragma unroll
    for (int s = 0; s < 2; ++s) {
#pragma unroll
      for (int i = 0; i < 4; ++i) {
        acc0[i] = __builtin_amdgcn_mfma_f32_16x16x32_bf16(afr[s][i], bf0[s], acc0[i], 0, 0, 0);
        if (DUAL)
          acc1[i] = __builtin_amdgcn_mfma_f32_16x16x32_bf16(afr[s][i], bf1[s], acc1[i], 0, 0, 0);
      }
    }
  }

  // epilogue: atomic accumulate (C/D layout: col=lane&15, row=(lane>>4)*4+reg)
#pragma unroll
  for (int i = 0; i < 4; ++i) {
#pragma unroll
    for (int r = 0; r < 4; ++r) {
      int row = wm * 64 + i * 16 + kq * 4 + r;
      size_t rbase = rowmap ? (size_t)rowmap[row] * ldc : (size_t)row * ldc;
      int col = bn * 32 + wn * 16 + fm;
      atomicAdd(&C0[rbase + col], acc0[i][r]);
      if (DUAL) atomicAdd(&C1[rbase + col], acc1[i][r]);
    }
  }
}

extern "C" void kernel_launch(void* const* d_in, const int* in_sizes, int n_in,
                              void* d_out, int out_size, void* d_ws, size_t ws_size,
                              hipStream_t stream) {
  const float* hid = (const float*)d_in[0];
  const float* rw  = (const float*)d_in[3];
  const float* rb  = (const float*)d_in[4];
  const float* ln1 = (const float*)d_in[5];
  const float* ln2 = (const float*)d_in[6];
  const float* wv  = (const float*)d_in[11];
  const float* bv  = (const float*)d_in[12];
  const float* wo  = (const float*)d_in[13];
  const float* wg  = (const float*)d_in[14];
  const float* wu  = (const float*)d_in[15];
  const float* wd  = (const float*)d_in[16];
  const int*   kp  = (const int*)d_in[17];
  float* out = (float*)d_out;

  char* ws = (char*)d_ws;
  float*          scores = (float*)(ws + 0);                // 1 KB
  int*            sel    = (int*)(ws + 1024);               // 512 B
  int*            pos    = (int*)(ws + 1536);               // 1 KB
  unsigned short* Hb     = (unsigned short*)(ws + 4096);    // 512 KB
  float*          V      = (float*)(ws + 528384);           // 1 MB
  float*          X1     = (float*)(ws + 1576960);          // 1 MB
  unsigned short* H2b    = (unsigned short*)(ws + 2625536); // 512 KB
  float*          G      = (float*)(ws + 3149824);          // 2.69 MB
  float*          U      = (float*)(ws + 5967872);          // 2.69 MB (contiguous with G)
  unsigned short* Mb     = (unsigned short*)(ws + 8785920); // 1.34 MB

  // zero G,U first (no deps; G..U contiguous 5636096 B = 352256 float4)
  k_zero<<<1024, 256, 0, stream>>>((float4*)G, 352256);
  k_router<<<256, 256, 0, stream>>>(hid, rw, rb, scores);
  k_select<<<1, 256, 0, stream>>>(scores, kp, sel, pos);
  k_rms1<<<128, 256, 0, stream>>>(hid, sel, ln1, bv, Hb, V, X1);
  // V += Hb @ wv   (64 n-tiles x 16 splits = 1024 blocks = 4/CU, KT=128: 2 iters)
  k_gemm<false, false><<<dim3(64, 16), 256, 0, stream>>>(
      Hb, wv, nullptr, V, nullptr, nullptr, 2048, 2048, 2048, 2048, 2048, 128, 2048);
  // X1 += V @ wo  (A fp32)
  k_gemm<true, false><<<dim3(64, 16), 256, 0, stream>>>(
      V, wo, nullptr, X1, nullptr, nullptr, 2048, 2048, 2048, 2048, 2048, 128, 2048);
  k_rms2<<<128, 256, 0, stream>>>(X1, ln2, H2b);
  // G,U += H2b @ {wg,wu}  (172 n-tiles x 8 splits = 1376 blocks ~ 5.4/CU, KT=256)
  k_gemm<false, true><<<dim3(172, 8), 256, 0, stream>>>(
      H2b, wg, wu, G, U, nullptr, 2048, 2048, 2048, 2048, 5504, 256, 5504);
  k_silu_out<<<1024, 256, 0, stream>>>(G, U, Mb, X1, pos, hid, out);
  // out[sel] += Mb @ wd  (64 x 16 = 1024 blocks, KT=384 -> K=6144 padded, 6 iters)
  k_gemm<false, false><<<dim3(64, 16), 256, 0, stream>>>(
      Mb, wd, nullptr, out, nullptr, sel, 6144, 5504, 5504, 5504, 2048, 384, 2048);
}

// Round 3
// 287.514 us; speedup vs baseline: 1.2440x; 1.0752x over previous
//
#include <hip/hip_runtime.h>
#include <hip/hip_bf16.h>
#include <stdint.h>

// T=1 => softmax over size-1 axis == 1 => attention output == V; q/k/RoPE dead.
// Pipeline: zero(G,U) -> router -> top-128 -> rms1 (V=bv, X1=x, Hb) ->
// V += Hb@wv -> X1 += V@wo -> rms2 -> G,U += H2b@{Wg,Wu} (dual) ->
// Mb=silu(G)*U + out copy/scatter -> out[sel] += Mb@Wd.
//
// GEMM (round-5): counted-vmcnt pipeline. __syncthreads carries a workgroup
// fence -> compiler emits s_waitcnt vmcnt(0) at EVERY barrier, draining the
// prefetched loads and collapsing the in-flight duty cycle (rounds 0-2 all
// plateau at 1.4-1.6 TB/s for this reason, independent of occupancy).
// Fix: raw __builtin_amdgcn_s_barrier() (no fence) + explicit lgkmcnt(0)
// before the writes-visible barrier + DEPTH-2 register prefetch (ra/rb).
// The register scoreboard then emits counted vmcnt waits at the ds_write
// consume point: one tile's loads (12-20/wave) stay in flight at all times.
// sched_barrier(0) after each barrier pins LDS ops/MFMAs (guide rule #18).
// Splits reverted to minimize atomic traffic (round-2's 16-split WRITE_SIZE
// doubling): G1/G2/G4 = 8 splits, G3 = 4 splits.

#define D_ 2048
#define I_ 5504
#define NROWS 256
#define KSEL 128

typedef __attribute__((ext_vector_type(8))) short short8;   // 8 x bf16
typedef __attribute__((ext_vector_type(4))) float floatx4;  // MFMA acc

__device__ __forceinline__ unsigned int pk2(float lo, float hi) {
  __hip_bfloat162 h = __float22bfloat162_rn(float2{lo, hi});  // v_cvt_pk_bf16_f32
  unsigned int u; __builtin_memcpy(&u, &h, 4); return u;
}

// ---------------- K0: zero G,U (contiguous 5636096 B) ----------------
__global__ void k_zero(float4* __restrict__ p, int n4) {
  int i = blockIdx.x * 256 + threadIdx.x;
  int st = gridDim.x * 256;
  for (; i < n4; i += st) p[i] = float4{0.f, 0.f, 0.f, 0.f};
}

// ---------------- K1: router scores ----------------
__global__ void k_router(const float* __restrict__ hid, const float* __restrict__ rw,
                         const float* __restrict__ rb, float* __restrict__ scores) {
  int b = blockIdx.x, t = threadIdx.x;
  const float4* x4 = (const float4*)(hid + (size_t)b * D_);
  const float4* w4 = (const float4*)rw;
  float s = 0.f;
#pragma unroll
  for (int c = 0; c < 2; ++c) {
    float4 xv = x4[t + c * 256], wv = w4[t + c * 256];
    s += xv.x * wv.x + xv.y * wv.y + xv.z * wv.z + xv.w * wv.w;
  }
  for (int o = 32; o; o >>= 1) s += __shfl_down(s, o);
  __shared__ float red[4];
  if ((t & 63) == 0) red[t >> 6] = s;
  __syncthreads();
  if (t == 0) scores[b] = red[0] + red[1] + red[2] + red[3] + rb[0];
}

// ---------------- K2: exact top-k, deterministic (rank == slot) ----------------
__global__ void k_select(const float* __restrict__ scores, const int* __restrict__ kptr,
                         int* __restrict__ sel, int* __restrict__ pos) {
  __shared__ float sv[NROWS];
  int t = threadIdx.x;
  sv[t] = scores[t];
  __syncthreads();
  float s = sv[t];
  int c = 0;
  for (int j = 0; j < NROWS; ++j) {
    float o = sv[j];
    c += (o > s) || (o == s && j < t);
  }
  int k = *kptr;                 // k_sel == 128 (grids sized for it)
  if (c < k) sel[c] = t;
  pos[t] = (c < k) ? c : -1;
}

// ---------------- K3: rms1, init V=bv, X1=x, H bf16 ----------------
__global__ void k_rms1(const float* __restrict__ hid, const int* __restrict__ sel,
                       const float* __restrict__ ln1, const float* __restrict__ bv,
                       unsigned short* __restrict__ Hb, float* __restrict__ V,
                       float* __restrict__ X1) {
  int i = blockIdx.x, t = threadIdx.x;
  int r = sel[i];
  const float4* x4 = (const float4*)(hid + (size_t)r * D_);
  float4 xa = x4[2 * t], xb = x4[2 * t + 1];
  float ss = xa.x * xa.x + xa.y * xa.y + xa.z * xa.z + xa.w * xa.w
           + xb.x * xb.x + xb.y * xb.y + xb.z * xb.z + xb.w * xb.w;
  for (int o = 32; o; o >>= 1) ss += __shfl_down(ss, o);
  __shared__ float red[4];
  if ((t & 63) == 0) red[t >> 6] = ss;
  __syncthreads();
  float inv = rsqrtf((red[0] + red[1] + red[2] + red[3]) * (1.0f / D_) + 1e-6f);
  const float4* w4 = (const float4*)ln1;
  float4 wa = w4[2 * t], wb = w4[2 * t + 1];
  union { unsigned int u[4]; uint4 q; } pk;
  pk.u[0] = pk2(xa.x * inv * wa.x, xa.y * inv * wa.y);
  pk.u[1] = pk2(xa.z * inv * wa.z, xa.w * inv * wa.w);
  pk.u[2] = pk2(xb.x * inv * wb.x, xb.y * inv * wb.y);
  pk.u[3] = pk2(xb.z * inv * wb.z, xb.w * inv * wb.w);
  ((uint4*)(Hb + (size_t)i * D_))[t] = pk.q;
  const float4* b4 = (const float4*)bv;
  float4* V4 = (float4*)(V + (size_t)i * D_);
  V4[2 * t] = b4[2 * t]; V4[2 * t + 1] = b4[2 * t + 1];
  float4* X4 = (float4*)(X1 + (size_t)i * D_);
  X4[2 * t] = xa; X4[2 * t + 1] = xb;
}

// ---------------- K5: rms2 (G/U zeroing in k_zero) ----------------
__global__ void k_rms2(const float* __restrict__ X1, const float* __restrict__ ln2,
                       unsigned short* __restrict__ H2b) {
  int i = blockIdx.x, t = threadIdx.x;
  const float4* x4 = (const float4*)(X1 + (size_t)i * D_);
  float4 xa = x4[2 * t], xb = x4[2 * t + 1];
  float ss = xa.x * xa.x + xa.y * xa.y + xa.z * xa.z + xa.w * xa.w
           + xb.x * xb.x + xb.y * xb.y + xb.z * xb.z + xb.w * xb.w;
  for (int o = 32; o; o >>= 1) ss += __shfl_down(ss, o);
  __shared__ float red[4];
  if ((t & 63) == 0) red[t >> 6] = ss;
  __syncthreads();
  float inv = rsqrtf((red[0] + red[1] + red[2] + red[3]) * (1.0f / D_) + 1e-6f);
  const float4* w4 = (const float4*)ln2;
  float4 wa = w4[2 * t], wb = w4[2 * t + 1];
  union { unsigned int u[4]; uint4 q; } pk;
  pk.u[0] = pk2(xa.x * inv * wa.x, xa.y * inv * wa.y);
  pk.u[1] = pk2(xa.z * inv * wa.z, xa.w * inv * wa.w);
  pk.u[2] = pk2(xb.x * inv * wb.x, xb.y * inv * wb.y);
  pk.u[3] = pk2(xb.z * inv * wb.z, xb.w * inv * wb.w);
  ((uint4*)(H2b + (size_t)i * D_))[t] = pk.q;
}

// ---------------- K7: Mb = silu(G)*U ; out = copy/scatter ----------------
__global__ void k_silu_out(const float* __restrict__ G, const float* __restrict__ U,
                           unsigned short* __restrict__ Mb,
                           const float* __restrict__ X1, const int* __restrict__ pos,
                           const float* __restrict__ hid, float* __restrict__ out) {
  int tid = blockIdx.x * 256 + threadIdx.x;
  const int nM4 = KSEL * I_ / 4;    // 176128
  if (tid < nM4) {
    float4 g = ((const float4*)G)[tid], u = ((const float4*)U)[tid];
    float m0 = (g.x / (1.f + expf(-g.x))) * u.x;
    float m1 = (g.y / (1.f + expf(-g.y))) * u.y;
    float m2 = (g.z / (1.f + expf(-g.z))) * u.z;
    float m3 = (g.w / (1.f + expf(-g.w))) * u.w;
    uint2 o; o.x = pk2(m0, m1); o.y = pk2(m2, m3);
    ((uint2*)Mb)[tid] = o;
  }
  const int nO4 = NROWS * (D_ / 4);   // 131072 float4
  if (tid < nO4) {
    int row = tid >> 9;             // 512 float4 per row
    int c4 = tid & 511;
    int p = pos[row];
    ((float4*)out)[tid] = (p >= 0) ? ((const float4*)X1)[(size_t)p * 512 + c4]
                                   : ((const float4*)hid)[tid];
  }
}

// ---------------- GEMM: C[128xN] += A[128xKA] @ B[KbxN] ----------------
// 128x32 tile, BK=64, 4 waves (2 wm x 2 wn), 16x16x32 bf16 MFMA.
// Depth-2 register prefetch (ra/rb), raw s_barrier (no fence -> no vmcnt(0)
// drain), counted vmcnt waits auto-inserted at the ds_write consume point.
// A granules with col>=KA zero-filled, B rows clamped (x0 A => harmless).
template<bool AF32, bool DUAL>
__global__ __launch_bounds__(256, 2)
void k_gemm(const void* __restrict__ Ap, const float* __restrict__ B0,
            const float* __restrict__ B1, float* __restrict__ C0,
            float* __restrict__ C1, const int* __restrict__ rowmap,
            int K, int KA, int Kb, int lda, int N, int KT, int ldc) {
  constexpr int ST = 72;   // LDS stride (elems): 144 B rows, b128-aligned
  const int bn = blockIdx.x;
  const int kt0 = blockIdx.y * KT;
  const int kt1 = kt0 + KT;
  const int tid = threadIdx.x;
  const int lane = tid & 63;
  const int wave = tid >> 6;
  const int wm = wave >> 1, wn = wave & 1;
  const int fm = lane & 15, kq = lane >> 4;

  __shared__ alignas(16) unsigned short Asm[128 * ST];            // 18 KB
  __shared__ alignas(16) unsigned short Bsm0[32 * ST];            // 4.5 KB
  __shared__ alignas(16) unsigned short Bsm1[DUAL ? 32 * ST : 8];

  floatx4 acc0[4] = {};
  floatx4 acc1[4] = {};

  // A staging: bf16: pass r covers rows r*32+(tid>>3), k-granule (tid&7)*8
  //            fp32: pass r covers rows r*16+(tid>>4), k-granule (tid&15)*4
  const int arow = tid >> 3;
  const int akg  = (tid & 7) * 8;
  const int frow = tid >> 4;
  const int fkg  = (tid & 15) * 4;
  // B staging: thread -> (col bnn, 8-row group bk8); one ds_write_b128 per B
  const int bnn = tid & 31;
  const int bk8 = (tid >> 5) * 8;

  const unsigned short* Ab = AF32 ? nullptr : (const unsigned short*)Ap;
  const float*          Af = AF32 ? (const float*)Ap : nullptr;
  const float* B0c = B0 + (size_t)(bn * 32 + bnn);
  const float* B1c = DUAL ? B1 + (size_t)(bn * 32 + bnn) : nullptr;

  struct Regs {
    uint4 a4[4];        // bf16 A: 4 x (row, 16B granule)
    float4 af8[8];      // fp32 A: 8 x (row, 16B granule)
    float b0v[8], b1v[8];
  };

  auto load_tile = [&](Regs& R, int kt) {
    if constexpr (AF32) {
      const int c0 = kt + fkg;
      const bool ok = c0 < KA;
#pragma unroll
      for (int r = 0; r < 8; ++r) {
        const float* p = Af + (size_t)(r * 16 + frow) * lda + c0;
        R.af8[r] = ok ? *(const float4*)p : make_float4(0.f, 0.f, 0.f, 0.f);
      }
    } else {
      const int c0 = kt + akg;
      const bool ok = c0 < KA;
#pragma unroll
      for (int r = 0; r < 4; ++r) {
        const unsigned short* p = Ab + (size_t)(r * 32 + arow) * lda + c0;
        R.a4[r] = ok ? *(const uint4*)p : make_uint4(0u, 0u, 0u, 0u);
      }
    }
#pragma unroll
    for (int j = 0; j < 8; ++j) {
      int kr = kt + bk8 + j; kr = kr < Kb ? kr : Kb - 1;
      R.b0v[j] = B0c[(size_t)kr * N];
      if constexpr (DUAL) R.b1v[j] = B1c[(size_t)kr * N];
    }
  };

  auto store_lds = [&](Regs& R) {
    if constexpr (AF32) {
#pragma unroll
      for (int r = 0; r < 8; ++r) {
        uint2 w;
        w.x = pk2(R.af8[r].x, R.af8[r].y);
        w.y = pk2(R.af8[r].z, R.af8[r].w);
        *(uint2*)&Asm[(r * 16 + frow) * ST + fkg] = w;
      }
    } else {
#pragma unroll
      for (int r = 0; r < 4; ++r)
        *(uint4*)&Asm[(r * 32 + arow) * ST + akg] = R.a4[r];
    }
    uint4 bq;
    bq.x = pk2(R.b0v[0], R.b0v[1]); bq.y = pk2(R.b0v[2], R.b0v[3]);
    bq.z = pk2(R.b0v[4], R.b0v[5]); bq.w = pk2(R.b0v[6], R.b0v[7]);
    *(uint4*)&Bsm0[bnn * ST + bk8] = bq;
    if constexpr (DUAL) {
      uint4 cq;
      cq.x = pk2(R.b1v[0], R.b1v[1]); cq.y = pk2(R.b1v[2], R.b1v[3]);
      cq.z = pk2(R.b1v[4], R.b1v[5]); cq.w = pk2(R.b1v[6], R.b1v[7]);
      *(uint4*)&Bsm1[bnn * ST + bk8] = cq;
    }
  };

  auto mfma_phase = [&]() {
    short8 afr[2][4], bf0[2], bf1[2];
#pragma unroll
    for (int s = 0; s < 2; ++s) {
#pragma unroll
      for (int i = 0; i < 4; ++i)
        afr[s][i] = *(const short8*)&Asm[(wm * 64 + i * 16 + fm) * ST + s * 32 + kq * 8];
      bf0[s] = *(const short8*)&Bsm0[(wn * 16 + fm) * ST + s * 32 + kq * 8];
      if constexpr (DUAL)
        bf1[s] = *(const short8*)&Bsm1[(wn * 16 + fm) * ST + s * 32 + kq * 8];
    }
#pragma unroll
    for (int s = 0; s < 2; ++s) {
#pragma unroll
      for (int i = 0; i < 4; ++i) {
        acc0[i] = __builtin_amdgcn_mfma_f32_16x16x32_bf16(afr[s][i], bf0[s], acc0[i], 0, 0, 0);
        if constexpr (DUAL)
          acc1[i] = __builtin_amdgcn_mfma_f32_16x16x32_bf16(afr[s][i], bf1[s], acc1[i], 0, 0, 0);
      }
    }
  };

  // One pipeline stage: consume R (tile kt), reissue R's loads for kt+128.
  auto stage = [&](Regs& R, int kt) {
    __builtin_amdgcn_s_barrier();          // previous tile's readers done
    __builtin_amdgcn_sched_barrier(0);
    store_lds(R);                           // counted vmcnt wait on R's loads
    if (kt + 128 < kt1) load_tile(R, kt + 128);   // reissue 2-ahead
    asm volatile("s_waitcnt lgkmcnt(0)" ::: "memory");  // LDS writes retired
    __builtin_amdgcn_s_barrier();          // tile visible to all waves
    __builtin_amdgcn_sched_barrier(0);
    mfma_phase();
    __builtin_amdgcn_sched_barrier(0);     // pin reads/MFMAs before next barrier
  };

  Regs ra, rb;
  load_tile(ra, kt0);
  load_tile(rb, kt0 + 64);

  int kt = kt0;
  while (true) {
    stage(ra, kt);
    kt += 64; if (kt >= kt1) break;
    stage(rb, kt);
    kt += 64; if (kt >= kt1) break;
  }

  // epilogue: atomic accumulate (C/D layout: col=lane&15, row=(lane>>4)*4+reg)
#pragma unroll
  for (int i = 0; i < 4; ++i) {
#pragma unroll
    for (int r = 0; r < 4; ++r) {
      int row = wm * 64 + i * 16 + kq * 4 + r;
      size_t rbase = rowmap ? (size_t)rowmap[row] * ldc : (size_t)row * ldc;
      int col = bn * 32 + wn * 16 + fm;
      atomicAdd(&C0[rbase + col], acc0[i][r]);
      if constexpr (DUAL) atomicAdd(&C1[rbase + col], acc1[i][r]);
    }
  }
}

extern "C" void kernel_launch(void* const* d_in, const int* in_sizes, int n_in,
                              void* d_out, int out_size, void* d_ws, size_t ws_size,
                              hipStream_t stream) {
  const float* hid = (const float*)d_in[0];
  const float* rw  = (const float*)d_in[3];
  const float* rb  = (const float*)d_in[4];
  const float* ln1 = (const float*)d_in[5];
  const float* ln2 = (const float*)d_in[6];
  const float* wv  = (const float*)d_in[11];
  const float* bv  = (const float*)d_in[12];
  const float* wo  = (const float*)d_in[13];
  const float* wg  = (const float*)d_in[14];
  const float* wu  = (const float*)d_in[15];
  const float* wd  = (const float*)d_in[16];
  const int*   kp  = (const int*)d_in[17];
  float* out = (float*)d_out;

  char* ws = (char*)d_ws;
  float*          scores = (float*)(ws + 0);                // 1 KB
  int*            sel    = (int*)(ws + 1024);               // 512 B
  int*            pos    = (int*)(ws + 1536);               // 1 KB
  unsigned short* Hb     = (unsigned short*)(ws + 4096);    // 512 KB
  float*          V      = (float*)(ws + 528384);           // 1 MB
  float*          X1     = (float*)(ws + 1576960);          // 1 MB
  unsigned short* H2b    = (unsigned short*)(ws + 2625536); // 512 KB
  float*          G      = (float*)(ws + 3149824);          // 2.69 MB
  float*          U      = (float*)(ws + 5967872);          // 2.69 MB (contiguous with G)
  unsigned short* Mb     = (unsigned short*)(ws + 8785920); // 1.34 MB

  // zero G,U first (no deps; G..U contiguous 5636096 B = 352256 float4)
  k_zero<<<1024, 256, 0, stream>>>((float4*)G, 352256);
  k_router<<<256, 256, 0, stream>>>(hid, rw, rb, scores);
  k_select<<<1, 256, 0, stream>>>(scores, kp, sel, pos);
  k_rms1<<<128, 256, 0, stream>>>(hid, sel, ln1, bv, Hb, V, X1);
  // V += Hb @ wv   (64 n-tiles x 8 splits = 512 blocks, KT=256: 4 iters)
  k_gemm<false, false><<<dim3(64, 8), 256, 0, stream>>>(
      Hb, wv, nullptr, V, nullptr, nullptr, 2048, 2048, 2048, 2048, 2048, 256, 2048);
  // X1 += V @ wo  (A fp32)
  k_gemm<true, false><<<dim3(64, 8), 256, 0, stream>>>(
      V, wo, nullptr, X1, nullptr, nullptr, 2048, 2048, 2048, 2048, 2048, 256, 2048);
  k_rms2<<<128, 256, 0, stream>>>(X1, ln2, H2b);
  // G,U += H2b @ {wg,wu}  (172 n-tiles x 4 splits = 688 blocks, KT=512: 8 iters)
  k_gemm<false, true><<<dim3(172, 4), 256, 0, stream>>>(
      H2b, wg, wu, G, U, nullptr, 2048, 2048, 2048, 2048, 5504, 512, 5504);
  k_silu_out<<<1024, 256, 0, stream>>>(G, U, Mb, X1, pos, hid, out);
  // out[sel] += Mb @ wd  (64 x 8 = 512 blocks, KT=704 -> K=5632 padded, 11 iters)
  k_gemm<false, false><<<dim3(64, 8), 256, 0, stream>>>(
      Mb, wd, nullptr, out, nullptr, sel, 5632, 5504, 5504, 5504, 2048, 704, 2048);
}